// Round 1
// baseline (672.417 us; speedup 1.0000x reference)
//
#include <hip/hip_runtime.h>
#include <hip/hip_bf16.h>

typedef __attribute__((ext_vector_type(8))) short short8;
typedef __attribute__((ext_vector_type(4))) float floatx4;

__device__ __forceinline__ unsigned short f2b(float f) {
    union { float f; unsigned int u; } v; v.f = f;
    unsigned int u = v.u;
    return (unsigned short)((u + 0x7FFFu + ((u >> 16) & 1u)) >> 16);
}
__device__ __forceinline__ float b2f(unsigned short h) {
    union { unsigned int u; float f; } v; v.u = ((unsigned int)h) << 16;
    return v.f;
}

// ---------------------------------------------------------------------------
// Kernel 1: agg2[i,d] = (1/10) * sum_j features[ids2[i*10 + q/512]][q%512],
//           q = d*10+j  (faithful to the reshape(25600,512,10).mean(-1) quirk)
// One block per node i: stage the dense 10x512 block (20KB) in LDS, coalesced.
// ---------------------------------------------------------------------------
__global__ __launch_bounds__(256) void agg2_kernel(
    const float* __restrict__ feat, const int* __restrict__ ids2,
    unsigned short* __restrict__ agg2)
{
    __shared__ __align__(16) float buf[5120];
    __shared__ int sid[10];
    const int i = blockIdx.x;
    const int t = threadIdx.x;
    if (t < 10) sid[t] = ids2[i * 10 + t];
    __syncthreads();
#pragma unroll
    for (int p = 0; p < 5; ++p) {
        int q = p * 1024 + t * 4;          // stays inside one 512-row (q%512 mult of 4)
        int row = q >> 9, col = q & 511;
        *(float4*)&buf[q] = *(const float4*)&feat[(long)sid[row] * 512 + col];
    }
    __syncthreads();
#pragma unroll
    for (int h = 0; h < 2; ++h) {
        int d = t + h * 256;
        float s = 0.f;
#pragma unroll
        for (int j = 0; j < 10; ++j) s += buf[d * 10 + j];
        agg2[(long)i * 512 + d] = f2b(s * 0.1f);
    }
}

// ---------------------------------------------------------------------------
// Generic bf16 MFMA GEMM: C[m0+64, 128] = act(A @ W + bias), A fp32-gathered
// (GATHER) or dense bf16. BM=64, BN=128, BK=32, 4 waves, 16x16x32 bf16 MFMA.
// B staged in fragment order [kb(4)][n(128)][k8(8)] so frags are ds_read_b128.
// out is bf16 [M,256] with column offset colbase.
// ---------------------------------------------------------------------------
template<bool GATHER, bool RELU>
__global__ __launch_bounds__(256) void gemm_node(
    const void* __restrict__ Asrc, const int* __restrict__ ids,
    const float* __restrict__ W, const float* __restrict__ bias,
    unsigned short* __restrict__ out, int K, int lda, int colbase)
{
    __shared__ __align__(16) unsigned short A_s[64 * 40];     // row stride 40 (pad)
    __shared__ __align__(16) unsigned short B_s[4 * 128 * 8];
    __shared__ int s_ids[64];

    const int t   = threadIdx.x;
    const int m0  = blockIdx.x * 64;
    if (GATHER && t < 64) s_ids[t] = ids[m0 + t];

    const int lane = t & 63;
    const int w    = t >> 6;        // wave id: m-subtile
    const int q4   = lane >> 4;     // 0..3
    const int l16  = lane & 15;

    floatx4 acc[8];
#pragma unroll
    for (int i = 0; i < 8; ++i) acc[i] = (floatx4){0.f, 0.f, 0.f, 0.f};

    const int r   = t >> 2;         // A-stage row 0..63
    const int kk  = (t & 3) * 8;    // A-stage k offset
    const int nB  = t & 127;        // B-stage n
    const int kb2 = t >> 7;         // B-stage k-block base (0/1)

    if (GATHER) __syncthreads();    // s_ids visible before first A stage

    for (int k0 = 0; k0 < K; k0 += 32) {
        // ---- stage A (64x32 bf16) ----
        if (GATHER) {
            const float* fp = (const float*)Asrc + (long)s_ids[r] * lda + (k0 + kk);
            float4 v1 = *(const float4*)fp;
            float4 v2 = *(const float4*)(fp + 4);
            union { unsigned short us[8]; uint4 v; } tmp;
            tmp.us[0] = f2b(v1.x); tmp.us[1] = f2b(v1.y);
            tmp.us[2] = f2b(v1.z); tmp.us[3] = f2b(v1.w);
            tmp.us[4] = f2b(v2.x); tmp.us[5] = f2b(v2.y);
            tmp.us[6] = f2b(v2.z); tmp.us[7] = f2b(v2.w);
            *(uint4*)&A_s[r * 40 + kk] = tmp.v;
        } else {
            const unsigned short* ap =
                (const unsigned short*)Asrc + (long)(m0 + r) * lda + (k0 + kk);
            *(uint4*)&A_s[r * 40 + kk] = *(const uint4*)ap;
        }
        // ---- stage B (32x128 fp32 -> bf16, fragment order) ----
#pragma unroll
        for (int kb = kb2; kb < 4; kb += 2) {
            union { unsigned short us[8]; uint4 v; } tmp;
#pragma unroll
            for (int j = 0; j < 8; ++j)
                tmp.us[j] = f2b(W[(long)(k0 + kb * 8 + j) * 128 + nB]);
            *(uint4*)&B_s[(kb * 128 + nB) * 8] = tmp.v;
        }
        __syncthreads();
        // ---- compute: 8 n-tiles of 16x16x32 ----
        short8 av = *(const short8*)&A_s[(w * 16 + l16) * 40 + q4 * 8];
#pragma unroll
        for (int nt = 0; nt < 8; ++nt) {
            short8 bv = *(const short8*)&B_s[(q4 * 128 + nt * 16 + l16) * 8];
            acc[nt] = __builtin_amdgcn_mfma_f32_16x16x32_bf16(av, bv, acc[nt], 0, 0, 0);
        }
        __syncthreads();
    }
    // ---- epilogue: D row=(lane>>4)*4+reg, col=lane&15 (m89-verified layout) ----
#pragma unroll
    for (int nt = 0; nt < 8; ++nt) {
        int col = nt * 16 + l16;
        float bv = bias[col];
#pragma unroll
        for (int reg = 0; reg < 4; ++reg) {
            int rowl = w * 16 + q4 * 4 + reg;
            float v = acc[nt][reg] + bv;
            if (RELU) v = fmaxf(v, 0.f);
            out[(long)(m0 + rowl) * 256 + colbase + col] = f2b(v);
        }
    }
}

// ---------------------------------------------------------------------------
// Kernel 3: agg1[b,c] = (1/25) * sum_j h2.flat[b*6400 + c*25 + j]
// ---------------------------------------------------------------------------
__global__ __launch_bounds__(256) void agg1_kernel(
    const unsigned short* __restrict__ h2, unsigned short* __restrict__ agg1)
{
    __shared__ float buf[6400];
    const int b = blockIdx.x, t = threadIdx.x;
#pragma unroll
    for (int p = 0; p < 25; ++p) {
        int idx = p * 256 + t;
        buf[idx] = b2f(h2[(long)b * 6400 + idx]);
    }
    __syncthreads();
    float s = 0.f;
#pragma unroll
    for (int j = 0; j < 25; ++j) s += buf[t * 25 + j];
    agg1[(long)b * 256 + t] = f2b(s * 0.04f);
}

// ---------------------------------------------------------------------------
// Kernel 4b: out[b, c] = h1[b,:] @ Wfc[:, c] + bfc[c]   (fp32, N=41, K=256)
// ---------------------------------------------------------------------------
__global__ __launch_bounds__(64) void fc_kernel(
    const unsigned short* __restrict__ h1, const float* __restrict__ Wfc,
    const float* __restrict__ bfc, float* __restrict__ out)
{
    __shared__ float row[256];
    const int b = blockIdx.x, t = threadIdx.x;
#pragma unroll
    for (int p = 0; p < 4; ++p) row[p * 64 + t] = b2f(h1[(long)b * 256 + p * 64 + t]);
    __syncthreads();
    if (t < 41) {
        float s = bfc[t];
        for (int k = 0; k < 256; ++k) s += row[k] * Wfc[k * 41 + t];
        out[(long)b * 41 + t] = s;
    }
}

extern "C" void kernel_launch(void* const* d_in, const int* in_sizes, int n_in,
                              void* d_out, int out_size, void* d_ws, size_t ws_size,
                              hipStream_t stream) {
    const float* features = (const float*)d_in[0];
    const int*   ids0     = (const int*)d_in[1];
    const int*   ids1     = (const int*)d_in[2];
    const int*   ids2     = (const int*)d_in[3];
    const float* W2s      = (const float*)d_in[4];
    const float* b2s      = (const float*)d_in[5];
    const float* W2n      = (const float*)d_in[6];
    const float* b2n      = (const float*)d_in[7];
    const float* W1s      = (const float*)d_in[8];
    const float* b1s      = (const float*)d_in[9];
    const float* W1n      = (const float*)d_in[10];
    const float* b1n      = (const float*)d_in[11];
    const float* Wfc      = (const float*)d_in[12];
    const float* bfc      = (const float*)d_in[13];
    float* out = (float*)d_out;

    char* ws = (char*)d_ws;
    unsigned short* agg2b = (unsigned short*)(ws);                 // 25600*512*2 = 26,214,400
    unsigned short* h2b   = (unsigned short*)(ws + 26214400);      // 25600*256*2 = 13,107,200
    unsigned short* agg1b = (unsigned short*)(ws + 39321600);      // 1024*256*2  =    524,288
    unsigned short* h1b   = (unsigned short*)(ws + 39845888);      // 1024*256*2  =    524,288

    // 1) agg2 (quirky 10-mean over gathered f2 blocks)
    agg2_kernel<<<25600, 256, 0, stream>>>(features, ids2, agg2b);
    // 2) h2 = relu([f1@W2s+b2s | agg2@W2n+b2n])   [25600, 256] bf16
    gemm_node<true,  true ><<<400, 256, 0, stream>>>(features, ids1, W2s, b2s, h2b, 512, 512, 0);
    gemm_node<false, true ><<<400, 256, 0, stream>>>(agg2b,  nullptr, W2n, b2n, h2b, 512, 512, 128);
    // 3) agg1 (quirky 25-mean over h2 flat)        [1024, 256] bf16
    agg1_kernel<<<1024, 256, 0, stream>>>(h2b, agg1b);
    // 4) h1 = [f0@W1s+b1s | agg1@W1n+b1n]  (no relu)  [1024, 256] bf16
    gemm_node<true,  false><<<16, 256, 0, stream>>>(features, ids0, W1s, b1s, h1b, 512, 512, 0);
    gemm_node<false, false><<<16, 256, 0, stream>>>(agg1b, nullptr, W1n, b1n, h1b, 256, 256, 128);
    // 5) out = h1 @ Wfc + bfc  [1024, 41] fp32
    fc_kernel<<<1024, 64, 0, stream>>>(h1b, Wfc, bfc, out);
}

// Round 2
// 618.019 us; speedup vs baseline: 1.0880x; 1.0880x over previous
//
#include <hip/hip_runtime.h>
#include <hip/hip_bf16.h>

typedef __attribute__((ext_vector_type(8))) short short8;
typedef __attribute__((ext_vector_type(4))) float floatx4;

static __device__ __forceinline__ unsigned short f2b(float f) {
    union { float f; unsigned int u; } v; v.f = f;
    unsigned int u = v.u;
    return (unsigned short)((u + 0x7FFFu + ((u >> 16) & 1u)) >> 16);
}
static __device__ __forceinline__ float b2f(unsigned short h) {
    union { unsigned int u; float f; } v; v.u = ((unsigned int)h) << 16;
    return v.f;
}

// async global->LDS DMA, 16B per lane; LDS dest = uniform base + lane*16
#define GLDS16(gp, lp)                                                         \
    __builtin_amdgcn_global_load_lds(                                          \
        (const __attribute__((address_space(1))) unsigned int*)(gp),           \
        (__attribute__((address_space(3))) unsigned int*)(lp), 16, 0, 0)

// ---------------------------------------------------------------------------
// Weight prep: fp32 [K x 128] -> bf16 fragment layout
// Wfrag[((kb32*4 + kb)*128 + n)*8 + k8] = bf16(W[(kb32*32 + kb*8 + k8)*128 + n])
// so a 32-k B-tile is one 8 KB contiguous chunk, DMA-able by global_load_lds.
// ---------------------------------------------------------------------------
__global__ __launch_bounds__(256) void prep_w(
    const float* __restrict__ W2s, const float* __restrict__ W2n,
    const float* __restrict__ W1s, const float* __restrict__ W1n,
    unsigned short* __restrict__ F2s, unsigned short* __restrict__ F2n,
    unsigned short* __restrict__ F1s, unsigned short* __restrict__ F1n)
{
    const int b = blockIdx.x, t = threadIdx.x;
    const float* src; unsigned short* dst; int o;
    if (b < 256)      { src = W2s; dst = F2s; o = b * 256 + t; }
    else if (b < 512) { src = W2n; dst = F2n; o = (b - 256) * 256 + t; }
    else if (b < 768) { src = W1s; dst = F1s; o = (b - 512) * 256 + t; }
    else              { src = W1n; dst = F1n; o = (b - 768) * 256 + t; }
    const int k8 = o & 7, n = (o >> 3) & 127, kb = (o >> 10) & 3, kb32 = o >> 12;
    const int k = kb32 * 32 + kb * 8 + k8;
    dst[o] = f2b(src[k * 128 + n]);
}

// ---------------------------------------------------------------------------
// GEMM body: C[m0+BM, 128] = act(A @ W + bias) into out[:,colbase..colbase+128)
// BM=64: wave w owns m-subtile w, all 8 n-tiles.
// BM=32: wave w owns m-subtile (w&1), n-half (w>>1) (4 n-tiles).
// B staged via global_load_lds from fragment-layout weights (8 KB / k-step).
// ---------------------------------------------------------------------------
template<int BM, bool GATHER, bool RELU>
__device__ __forceinline__ void gemm_body(
    const void* __restrict__ Asrc, const int* __restrict__ ids,
    const unsigned short* __restrict__ Wfrag, const float* __restrict__ bias,
    unsigned short* __restrict__ out, int K, int lda, int colbase, int m0,
    unsigned short* A_s /*BM*40*/, unsigned short* B_s /*4096 elem*/, int* s_ids)
{
    const int t = threadIdx.x;
    if (GATHER && t < BM) s_ids[t] = ids[m0 + t];

    const int lane = t & 63;
    const int w    = t >> 6;
    const int q4   = lane >> 4;
    const int l16  = lane & 15;

    const int wm  = (BM == 64) ? w * 16 : (w & 1) * 16;
    const int wn0 = (BM == 64) ? 0      : (w >> 1) * 64;
    constexpr int NT = (BM == 64) ? 8 : 4;

    floatx4 acc[NT];
#pragma unroll
    for (int i = 0; i < NT; ++i) acc[i] = (floatx4){0.f, 0.f, 0.f, 0.f};

    const int r  = t >> 2;          // A-stage row
    const int kk = (t & 3) * 8;     // A-stage k offset

    if (GATHER) __syncthreads();    // s_ids visible

    const int nkb = K >> 5;
    for (int kb32 = 0; kb32 < nkb; ++kb32) {
        const int k0 = kb32 * 32;
        // ---- stage A (BM x 32 bf16, padded stride 40) ----
        if (BM == 64 || t < 128) {
            if (GATHER) {
                const float* fp = (const float*)Asrc + (long)s_ids[r] * lda + (k0 + kk);
                float4 v1 = *(const float4*)fp;
                float4 v2 = *(const float4*)(fp + 4);
                union { unsigned short us[8]; uint4 v; } tmp;
                tmp.us[0] = f2b(v1.x); tmp.us[1] = f2b(v1.y);
                tmp.us[2] = f2b(v1.z); tmp.us[3] = f2b(v1.w);
                tmp.us[4] = f2b(v2.x); tmp.us[5] = f2b(v2.y);
                tmp.us[6] = f2b(v2.z); tmp.us[7] = f2b(v2.w);
                *(uint4*)&A_s[r * 40 + kk] = tmp.v;
            } else {
                const unsigned short* ap =
                    (const unsigned short*)Asrc + (long)(m0 + r) * lda + (k0 + kk);
                *(uint4*)&A_s[r * 40 + kk] = *(const uint4*)ap;
            }
        }
        // ---- stage B: 8 KB fragment chunk via async DMA (2 x 1KB per wave) ----
        {
            const char* gb = (const char*)Wfrag + (size_t)kb32 * 8192 + (size_t)lane * 16;
            GLDS16(gb + (w * 2 + 0) * 1024, (char*)B_s + (w * 2 + 0) * 1024);
            GLDS16(gb + (w * 2 + 1) * 1024, (char*)B_s + (w * 2 + 1) * 1024);
        }
        __syncthreads();   // drains vmcnt (DMA) + lgkmcnt (ds_write)
        // ---- compute ----
        short8 av = *(const short8*)&A_s[(wm + l16) * 40 + q4 * 8];
#pragma unroll
        for (int nt = 0; nt < NT; ++nt) {
            short8 bv = *(const short8*)&B_s[(q4 * 128 + wn0 + nt * 16 + l16) * 8];
            acc[nt] = __builtin_amdgcn_mfma_f32_16x16x32_bf16(av, bv, acc[nt], 0, 0, 0);
        }
        __syncthreads();
    }
    // ---- epilogue: D row=(lane>>4)*4+reg, col=lane&15 ----
#pragma unroll
    for (int nt = 0; nt < NT; ++nt) {
        const int col = wn0 + nt * 16 + l16;
        const float bv = bias[col];
#pragma unroll
        for (int reg = 0; reg < 4; ++reg) {
            const int rowl = wm + q4 * 4 + reg;
            float v = acc[nt][reg] + bv;
            if (RELU) v = fmaxf(v, 0.f);
            out[(long)(m0 + rowl) * 256 + colbase + col] = f2b(v);
        }
    }
}

// ---------------------------------------------------------------------------
// Fused: blocks [0,400) = layer-2 self GEMM (f1-gather @ W2s -> h2[:,0:128));
//        blocks [400, 26000) = agg2 (quirky 10-mean of gathered f2 blocks).
// gemm blocks dispatch first and overlap with the memory-bound agg2 phase.
// ---------------------------------------------------------------------------
__global__ __launch_bounds__(256) void fused_agg2_gemm(
    const float* __restrict__ feat, const int* __restrict__ ids2,
    unsigned short* __restrict__ agg2, const int* __restrict__ ids1,
    const unsigned short* __restrict__ F2s, const float* __restrict__ b2s,
    unsigned short* __restrict__ h2)
{
    __shared__ __align__(16) char smem[20736];
    const int b = blockIdx.x;
    const int t = threadIdx.x;
    if (b < 400) {
        unsigned short* A_s = (unsigned short*)smem;           // 5120 B
        unsigned short* B_s = (unsigned short*)(smem + 5120);  // 8192 B
        int* s_ids = (int*)(smem + 13312);                     // 256 B
        gemm_body<64, true, true>(feat, ids1, F2s, b2s, h2, 512, 512, 0,
                                  b * 64, A_s, B_s, s_ids);
    } else {
        float* buf = (float*)smem;                             // 20480 B
        int* sid = (int*)(smem + 20480);
        const int i = b - 400;
        if (t < 10) sid[t] = ids2[i * 10 + t];
        __syncthreads();
#pragma unroll
        for (int p = 0; p < 5; ++p) {
            int q = p * 1024 + t * 4;
            int row = q >> 9, col = q & 511;
            *(float4*)&buf[q] = *(const float4*)&feat[(long)sid[row] * 512 + col];
        }
        __syncthreads();
#pragma unroll
        for (int h = 0; h < 2; ++h) {
            int d = t + h * 256;
            float s = 0.f;
#pragma unroll
            for (int j = 0; j < 10; ++j) s += buf[d * 10 + j];
            agg2[(long)i * 512 + d] = f2b(s * 0.1f);
        }
    }
}

// layer-2 neighbor GEMM: agg2 @ W2n -> h2[:,128:256)
__global__ __launch_bounds__(256) void gemm_n2(
    const unsigned short* __restrict__ agg2b, const unsigned short* __restrict__ F2n,
    const float* __restrict__ b2n, unsigned short* __restrict__ h2)
{
    __shared__ __align__(16) unsigned short A_s[64 * 40];
    __shared__ __align__(16) unsigned short B_s[4096];
    __shared__ int s_ids[64];
    gemm_body<64, false, true>(agg2b, nullptr, F2n, b2n, h2, 512, 512, 128,
                               blockIdx.x * 64, A_s, B_s, s_ids);
}

// agg1[b,c] = (1/25) * sum_j h2.flat[b*6400 + c*25 + j]
__global__ __launch_bounds__(256) void agg1_kernel(
    const unsigned short* __restrict__ h2, unsigned short* __restrict__ agg1)
{
    __shared__ float buf[6400];
    const int b = blockIdx.x, t = threadIdx.x;
#pragma unroll
    for (int p = 0; p < 25; ++p) {
        int idx = p * 256 + t;
        buf[idx] = b2f(h2[(long)b * 6400 + idx]);
    }
    __syncthreads();
    float s = 0.f;
#pragma unroll
    for (int j = 0; j < 25; ++j) s += buf[t * 25 + j];
    agg1[(long)b * 256 + t] = f2b(s * 0.04f);
}

// Fused tail: blocks [0,32) = f0-gather @ W1s (K=512) -> h1[:,0:128)
//             blocks [32,64) = agg1 @ W1n (K=256)     -> h1[:,128:256)
__global__ __launch_bounds__(256) void tail_gemm(
    const float* __restrict__ feat, const int* __restrict__ ids0,
    const unsigned short* __restrict__ agg1b,
    const unsigned short* __restrict__ F1s, const unsigned short* __restrict__ F1n,
    const float* __restrict__ b1s, const float* __restrict__ b1n,
    unsigned short* __restrict__ h1)
{
    __shared__ __align__(16) unsigned short A_s[32 * 40];
    __shared__ __align__(16) unsigned short B_s[4096];
    __shared__ int s_ids[32];
    const int b = blockIdx.x;
    if (b < 32)
        gemm_body<32, true, false>(feat, ids0, F1s, b1s, h1, 512, 512, 0,
                                   b * 32, A_s, B_s, s_ids);
    else
        gemm_body<32, false, false>(agg1b, nullptr, F1n, b1n, h1, 256, 256, 128,
                                    (b - 32) * 32, A_s, B_s, s_ids);
}

// out[b,c] = h1[b,:] @ Wfc[:,c] + bfc[c]  (fp32, N=41, K=256)
__global__ __launch_bounds__(64) void fc_kernel(
    const unsigned short* __restrict__ h1, const float* __restrict__ Wfc,
    const float* __restrict__ bfc, float* __restrict__ out)
{
    __shared__ float row[256];
    const int b = blockIdx.x, t = threadIdx.x;
#pragma unroll
    for (int p = 0; p < 4; ++p) row[p * 64 + t] = b2f(h1[(long)b * 256 + p * 64 + t]);
    __syncthreads();
    if (t < 41) {
        float s = bfc[t];
        for (int k = 0; k < 256; ++k) s += row[k] * Wfc[k * 41 + t];
        out[(long)b * 41 + t] = s;
    }
}

extern "C" void kernel_launch(void* const* d_in, const int* in_sizes, int n_in,
                              void* d_out, int out_size, void* d_ws, size_t ws_size,
                              hipStream_t stream) {
    const float* features = (const float*)d_in[0];
    const int*   ids0     = (const int*)d_in[1];
    const int*   ids1     = (const int*)d_in[2];
    const int*   ids2     = (const int*)d_in[3];
    const float* W2s      = (const float*)d_in[4];
    const float* b2s      = (const float*)d_in[5];
    const float* W2n      = (const float*)d_in[6];
    const float* b2n      = (const float*)d_in[7];
    const float* W1s      = (const float*)d_in[8];
    const float* b1s      = (const float*)d_in[9];
    const float* W1n      = (const float*)d_in[10];
    const float* b1n      = (const float*)d_in[11];
    const float* Wfc      = (const float*)d_in[12];
    const float* bfc      = (const float*)d_in[13];
    float* out = (float*)d_out;

    char* ws = (char*)d_ws;
    unsigned short* agg2b = (unsigned short*)(ws);                 // 26,214,400 B
    unsigned short* h2b   = (unsigned short*)(ws + 26214400);      // 13,107,200 B
    unsigned short* agg1b = (unsigned short*)(ws + 39321600);      //    524,288 B
    unsigned short* h1b   = (unsigned short*)(ws + 39845888);      //    524,288 B
    unsigned short* F2s   = (unsigned short*)(ws + 40370176);      //    131,072 B
    unsigned short* F2n   = (unsigned short*)(ws + 40501248);      //    131,072 B
    unsigned short* F1s   = (unsigned short*)(ws + 40632320);      //    131,072 B
    unsigned short* F1n   = (unsigned short*)(ws + 40763392);      //     65,536 B

    // 0) weights -> bf16 fragment layout
    prep_w<<<896, 256, 0, stream>>>(W2s, W2n, W1s, W1n, F2s, F2n, F1s, F1n);
    // 1) fused: layer-2 self GEMM (400 blocks) + agg2 (25600 blocks)
    fused_agg2_gemm<<<26000, 256, 0, stream>>>(features, ids2, agg2b, ids1, F2s, b2s, h2b);
    // 2) layer-2 neighbor GEMM
    gemm_n2<<<400, 256, 0, stream>>>(agg2b, F2n, b2n, h2b);
    // 3) agg1
    agg1_kernel<<<1024, 256, 0, stream>>>(h2b, agg1b);
    // 4) fused tail GEMMs -> h1
    tail_gemm<<<64, 256, 0, stream>>>(features, ids0, agg1b, F1s, F1n, b1s, b1n, h1b);
    // 5) fc -> out
    fc_kernel<<<1024, 64, 0, stream>>>(h1b, Wfc, bfc, out);
}